// Round 3
// 435.349 us; speedup vs baseline: 1.0486x; 1.0486x over previous
//
#include <hip/hip_runtime.h>
#include <math.h>

// Problem constants (from reference)
#define T_TOK 4096
#define D_DIM 2048
#define NEXP  64
#define CAP   160            // floor(2*1.25*4096/64)=160, even, >=4

// Kernel-1 config
#define TPB   4              // tokens per GEMM block (one wave per token at reduce)
#define NGB   (T_TOK / TPB)  // 1024 GEMM blocks
#define NZB   2048           // zero-fill blocks

typedef float vfloat4 __attribute__((ext_vector_type(4)));

// ---------------------------------------------------------------------------
// Kernel 1 (unchanged): blocks [0,NGB) compute logits (register-resident GEMM,
// no LDS in the K-loop) + cross-wave K-reduce + shuffle top-2 + softmax ->
// workspace; blocks [NGB,NGB+NZB) zero-fill the output concurrently.
// This kernel is HBM-write-roofline-bound (out_size*4 bytes of mandatory
// nontemporal stores at ~6.4 TB/s); the GEMM fully hides under the fill.
// ---------------------------------------------------------------------------
__global__ __launch_bounds__(256) void fused_main(
    const float* __restrict__ x, const float* __restrict__ wg,
    float* __restrict__ out, int out_size,
    int* __restrict__ topi, float* __restrict__ topw)
{
    const int bid = blockIdx.x;
    const int tid = threadIdx.x;

    if (bid >= NGB) {
        // ---- zero-fill path (memory-roofline: must write out_size*4B) ----
        const int zb = bid - NGB;
        const size_t n4 = (size_t)out_size >> 2;
        vfloat4* o4 = (vfloat4*)out;
        const vfloat4 z = {0.f, 0.f, 0.f, 0.f};
        const size_t stride = (size_t)NZB * 256;
        for (size_t i = (size_t)zb * 256 + tid; i < n4; i += stride)
            __builtin_nontemporal_store(z, &o4[i]);
        if (zb == 0 && tid == 0) {
            for (size_t i = n4 << 2; i < (size_t)out_size; ++i) out[i] = 0.f;
        }
        return;
    }

    // ---- GEMM path ----
    const int e    = tid & 63;                                   // expert = lane
    const int w    = __builtin_amdgcn_readfirstlane(tid >> 6);   // wave id (uniform)
    const int tok0 = bid * TPB;
    const int wk0  = w * (D_DIM / 4);                            // this wave's K range

    float acc[TPB] = {0.f, 0.f, 0.f, 0.f};

    const float* __restrict__ wrow = wg + (size_t)e * D_DIM + wk0;

    for (int c = 0; c < (D_DIM / 4) / 32; ++c) {                 // 16 chunks of 32 k
        vfloat4 b[8];
#pragma unroll
        for (int j = 0; j < 8; ++j)
            b[j] = *(const vfloat4*)(wrow + c * 32 + j * 4);
#pragma unroll
        for (int t = 0; t < TPB; ++t) {
            const float* __restrict__ xp =
                x + (size_t)(tok0 + t) * D_DIM + wk0 + c * 32;   // wave-uniform addr
            float s = 0.f;
#pragma unroll
            for (int j = 0; j < 8; ++j) {
                s += xp[j*4+0] * b[j].x + xp[j*4+1] * b[j].y
                   + xp[j*4+2] * b[j].z + xp[j*4+3] * b[j].w;
            }
            acc[t] += s;
        }
    }

    // cross-wave K-reduce through 4KB LDS
    __shared__ float sAcc[4][TPB][NEXP];
#pragma unroll
    for (int t = 0; t < TPB; ++t)
        sAcc[w][t][e] = acc[t];
    __syncthreads();

    // wave w now owns token w of this block; lane = expert
    const int t = w;
    float v = sAcc[0][t][e] + sAcc[1][t][e] + sAcc[2][t][e] + sAcc[3][t][e];

    // top-2 via 6-step xor-butterfly; tie-break: lower index wins (lax.top_k)
    float v1 = v;         int i1 = e;
    float v2 = -INFINITY; int i2 = NEXP;
#pragma unroll
    for (int off = 32; off >= 1; off >>= 1) {
        const float ov1 = __shfl_xor(v1, off, 64);
        const int   oi1 = __shfl_xor(i1, off, 64);
        const float ov2 = __shfl_xor(v2, off, 64);
        const int   oi2 = __shfl_xor(i2, off, 64);
        const bool firstMine = (v1 > ov1) || (v1 == ov1 && i1 < oi1);
        const float n1  = firstMine ? v1  : ov1;
        const int   ni1 = firstMine ? i1  : oi1;
        const float c1  = firstMine ? ov1 : v1;    // loser of the firsts
        const int   ci1 = firstMine ? oi1 : i1;
        const float c2  = firstMine ? v2  : ov2;   // winner's second
        const int   ci2 = firstMine ? i2  : oi2;
        const bool secondC1 = (c1 > c2) || (c1 == c2 && ci1 < ci2);
        v1 = n1;                      i1 = ni1;
        v2 = secondC1 ? c1 : c2;      i2 = secondC1 ? ci1 : ci2;
    }

    if (e == 0) {
        const int gt = tok0 + t;
        const float r  = expf(v2 - v1);        // <= 1
        const float s1 = 1.0f / (1.0f + r);
        topi[2 * gt + 0] = i1;
        topi[2 * gt + 1] = i2;
        topw[2 * gt + 0] = s1;
        topw[2 * gt + 1] = r * s1;
    }
}

// ---------------------------------------------------------------------------
// Kernel 2: expert-parallel capacity assignment. 16 blocks x 4 waves = 64
// waves, one wave per expert. Each wave scans all T*K attempts in flat order;
// per 64-wide chunk, ballot(e == myE) gives the set of attempts to my expert;
// slot = running + popc(mask & lanes_below). The only loop-carried dependency
// is the scalar `running += popc(ballot)` (SALU) -- no LDS, no cross-lane
// serialization. Replaces the single-wave serial kernel (~25-30 us one-CU
// tail) with ~5 us at 64-wave parallelism. Semantics identical: flat-order
// ranking, slot>=CAP rejected but still counted, used = min(count, CAP).
// ---------------------------------------------------------------------------
__global__ __launch_bounds__(256) void scatter_assign(
    const int* __restrict__ topi, const float* __restrict__ topw,
    float* __restrict__ out)
{
    const int lane = threadIdx.x & 63;
    const int myE  = (blockIdx.x << 2) | (threadIdx.x >> 6);   // 0..63

    float* __restrict__ cb   = out + NEXP;
    float* __restrict__ mask = cb + (size_t)T_TOK * NEXP * CAP;

    const unsigned long long lt = ((unsigned long long)1 << lane) - 1ull;
    const int NCH = (T_TOK * 2) / 64;   // 128 chunks

    // prefetched stream of (expert, weight) for this lane's attempt slots
    int   e  = topi[lane];
    float tw = topw[lane];
    int   running = 0;

    for (int c = 0; c < NCH; ++c) {
        // prefetch next chunk (hides L2/HBM latency behind ballot work)
        int   en  = 0;
        float twn = 0.f;
        if (c + 1 < NCH) {
            en  = topi[(c + 1) * 64 + lane];
            twn = topw[(c + 1) * 64 + lane];
        }

        const unsigned long long m = __ballot(e == myE);
        if (e == myE) {
            const int slot = running + __popcll(m & lt);
            if (slot < CAP) {
                const int t = (c * 64 + lane) >> 1;
                const size_t off = ((size_t)t * NEXP + myE) * CAP + slot;
                cb[off]   = tw;
                mask[off] = 1.0f;
            }
        }
        running += __popcll(m);

        e = en; tw = twn;
    }

    if (lane == 0) {
        const int used = running < CAP ? running : CAP;
        out[myE] = (float)used;               // used_capacity as float
    }
}

// ---------------------------------------------------------------------------
extern "C" void kernel_launch(void* const* d_in, const int* in_sizes, int n_in,
                              void* d_out, int out_size, void* d_ws, size_t ws_size,
                              hipStream_t stream)
{
    const float* x  = (const float*)d_in[0];   // [4096, 2048]
    const float* wg = (const float*)d_in[1];   // [64, 2048]
    float* out = (float*)d_out;

    // workspace: 8192 ints (top indices) + 8192 floats (top weights) = 64 KB
    int*   topi = (int*)d_ws;
    float* topw = (float*)(topi + T_TOK * 2);

    fused_main<<<NGB + NZB, 256, 0, stream>>>(x, wg, out, out_size, topi, topw);
    scatter_assign<<<16, 256, 0, stream>>>(topi, topw, out);
}